// Round 1
// baseline (905.902 us; speedup 1.0000x reference)
//
#include <hip/hip_runtime.h>

typedef unsigned short u16;
typedef __bf16 bf16x8 __attribute__((ext_vector_type(8)));
typedef float f32x4 __attribute__((ext_vector_type(4)));

#define B_   256
#define C_   2048
#define P_   196
#define A_   512
#define CP_  (C_ * P_)        // 401408
#define MTOT (B_ * P_)        // 50176 = 784 * 64

#define BM 64                 // rows per block
#define BK 32                 // k per iter (one 16x16x32 kstep)
#define NBLK (MTOT / BM)      // 784

__device__ __forceinline__ u16 f2bf(float f) {
    unsigned int x = __float_as_uint(f);
    unsigned int r = (x + 0x7fffu + ((x >> 16) & 1u)) >> 16;   // RNE
    return (u16)r;
}

__device__ __forceinline__ unsigned long long pack4bf(const float* v) {
    unsigned int lo = (unsigned int)f2bf(v[0]) | ((unsigned int)f2bf(v[1]) << 16);
    unsigned int hi = (unsigned int)f2bf(v[2]) | ((unsigned int)f2bf(v[3]) << 16);
    return (unsigned long long)lo | ((unsigned long long)hi << 32);
}

// Raw workgroup barrier: waits ONLY lgkm (LDS write visibility), leaves
// global/L2 register loads in flight across the barrier (unlike
// __syncthreads(), which drains vmcnt(0)).  Single asm so no memory op can
// be scheduled between the wait and the barrier.
#define WG_BARRIER() asm volatile("s_waitcnt lgkmcnt(0)\n\ts_barrier" ::: "memory")

// ---------------------------------------------------------------------------
// Kernel 1: Wt[a][c] = bf16(W_enc[c][a])   (2048x512 -> 512x2048)
// ---------------------------------------------------------------------------
__global__ __launch_bounds__(256) void k_transpose_wenc(const float* __restrict__ W,
                                                        u16* __restrict__ Wt) {
    __shared__ u16 tile[64][65];
    int t  = threadIdx.x;
    int cb = (blockIdx.x & 31) * 64;
    int ab = (blockIdx.x >> 5) * 64;
#pragma unroll
    for (int i = 0; i < 16; ++i) {
        int c = (t >> 6) + i * 4;
        int a = t & 63;
        tile[c][a] = f2bf(W[(size_t)(cb + c) * A_ + ab + a]);
    }
    __syncthreads();
#pragma unroll
    for (int i = 0; i < 16; ++i) {
        int a  = (t >> 6) + i * 4;
        int cl = t & 63;
        Wt[(size_t)(ab + a) * C_ + cb + cl] = tile[cl][a];
    }
}

// ---------------------------------------------------------------------------
// Kernel 2: dec_att[b][a] = dh[b] @ W_dec[:,a] + b_dec[a]
// ---------------------------------------------------------------------------
__global__ __launch_bounds__(512) void k_dec_att(const float* __restrict__ dh,
                                                 const float* __restrict__ Wd,
                                                 const float* __restrict__ bd,
                                                 float* __restrict__ out) {
    __shared__ float hL[512];
    int b = blockIdx.x, t = threadIdx.x;
    hL[t] = dh[b * 512 + t];
    __syncthreads();
    float s = bd[t];
#pragma unroll 8
    for (int k = 0; k < 512; ++k) s = fmaf(hL[k], Wd[k * 512 + t], s);
    out[b * 512 + t] = s;
}

// ---------------------------------------------------------------------------
// Kernel 3: fused att GEMM, rebuilt for latency tolerance.
//   Block: 512 thr = 8 waves, tile 64 rows x 512 a, K=2048, BK=32.
//   Wave w owns a-slice [w*64, w*64+64): acc 4x4 of 16x16 frags (64 AGPR).
//   B-operand (Wt) is L2-resident (2 MB): loaded straight into registers per
//     wave each k-step (16 rows x 64B contiguous segments) -- no LDS, no DMA.
//   A-operand (feats) staged in LDS (only 8 KB double-buffered; total LDS
//     16 KB -> 2 blocks/CU for cross-block overlap).
//   K-loop barriers are raw lgkm-only (WG_BARRIER): the HBM A-gather and L2
//     B loads are never drained at a barrier; A is prefetched 2 iterations
//     deep via manual unroll-2 (static register alternation).
// ---------------------------------------------------------------------------
__global__ __launch_bounds__(512, 4) void k_gemm_att(const float* __restrict__ enc,
                                                     const u16* __restrict__ Wt,
                                                     const float* __restrict__ dec_att,
                                                     const float* __restrict__ benc,
                                                     const float* __restrict__ wfull,
                                                     const float* __restrict__ bfull,
                                                     float* __restrict__ att) {
    __shared__ u16   As[2][4 * 512];     // 4 KB/buf: 64 rows x 32 k, frag order
    __shared__ float decL[2][512];
    __shared__ float wL[512];
    __shared__ float att_part[8][64];

    const int t    = threadIdx.x;
    const int lane = t & 63;
    const int wa   = t >> 6;             // 0..7 : wave = 64-wide a-slice
    const int l16  = lane & 15;
    const int lq   = lane >> 4;
    const int row0 = blockIdx.x * BM;

    const int b0 = row0 / 196;
    const int b1 = (row0 + BM - 1) / 196;
    decL[0][t] = dec_att[b0 * 512 + t] + benc[t];
    decL[1][t] = dec_att[b1 * 512 + t] + benc[t];
    wL[t] = wfull[t];

    // ---- A (feats) staging map: thread = (pl, kq); 4 elems, k = kq*4+j ----
    const int kq = t & 7;                // 8 k-quads of 4
    const int pl = t >> 3;               // 0..63 local row
    const int pg = row0 + pl;
    const int bb = pg / 196;
    const int pp = pg - bb * 196;
    const float* srcA = enc + (size_t)bb * CP_ + (size_t)(kq * 4) * P_ + pp;
    // frag slot: lane16 = (pl&15) + 16*(kq>>1), u16 sub-off (kq&1)*4
    const int a_off = (pl >> 4) * 512 + ((pl & 15) + 16 * (kq >> 1)) * 8 + (kq & 1) * 4;

    // ---- B (Wt) per-wave register gather: lane l, frag ta reads 16B at
    //      Wt[(wa*64 + ta*16 + (l&15))*C_ + k*32 + (l>>4)*8]  (A-operand layout)
    const u16* srcB = Wt + (size_t)(wa * 64 + l16) * C_ + lq * 8;

    f32x4 acc[4][4] = {};                // [ta][tr]

    // ---- prologue ---------------------------------------------------------
    float av0[4], av1[4];
#pragma unroll
    for (int j = 0; j < 4; ++j) av0[j] = srcA[(size_t)j * P_];              // k=0
    *(unsigned long long*)&As[0][a_off] = pack4bf(av0);
#pragma unroll
    for (int j = 0; j < 4; ++j) av1[j] = srcA[(size_t)BK * P_ + (size_t)j * P_]; // k=1
    bf16x8 bcur[4];
#pragma unroll
    for (int ta = 0; ta < 4; ++ta)
        bcur[ta] = *(const bf16x8*)(srcB + (size_t)(ta * 16) * C_);         // k=0
    WG_BARRIER();                        // As[0] visible; loads stay in flight

    for (int k = 0; k < C_ / BK; k += 2) {
        // ======== even sub-iter: compute k, As[0] -> write As[1] (k+1) ====
        bf16x8 bfr[4];
#pragma unroll
        for (int tr = 0; tr < 4; ++tr)
            bfr[tr] = *(const bf16x8*)&As[0][tr * 512 + lane * 8];
        if (k + 2 < C_ / BK) {           // issue HBM A-gather for k+2
#pragma unroll
            for (int j = 0; j < 4; ++j)
                av0[j] = srcA[(size_t)(k + 2) * BK * P_ + (size_t)j * P_];
        }
#pragma unroll
        for (int ta = 0; ta < 4; ++ta)
#pragma unroll
            for (int tr = 0; tr < 4; ++tr)
                acc[ta][tr] = __builtin_amdgcn_mfma_f32_16x16x32_bf16(bcur[ta], bfr[tr],
                                                                      acc[ta][tr], 0, 0, 0);
#pragma unroll
        for (int ta = 0; ta < 4; ++ta)   // issue L2 B-frags for k+1
            bcur[ta] = *(const bf16x8*)(srcB + (size_t)(ta * 16) * C_ + (size_t)(k + 1) * 32);
        *(unsigned long long*)&As[1][a_off] = pack4bf(av1);   // waits av1 vmcnt only
        WG_BARRIER();

        // ======== odd sub-iter: compute k+1, As[1] -> write As[0] (k+2) ==
#pragma unroll
        for (int tr = 0; tr < 4; ++tr)
            bfr[tr] = *(const bf16x8*)&As[1][tr * 512 + lane * 8];
        if (k + 3 < C_ / BK) {           // issue HBM A-gather for k+3
#pragma unroll
            for (int j = 0; j < 4; ++j)
                av1[j] = srcA[(size_t)(k + 3) * BK * P_ + (size_t)j * P_];
        }
#pragma unroll
        for (int ta = 0; ta < 4; ++ta)
#pragma unroll
            for (int tr = 0; tr < 4; ++tr)
                acc[ta][tr] = __builtin_amdgcn_mfma_f32_16x16x32_bf16(bcur[ta], bfr[tr],
                                                                      acc[ta][tr], 0, 0, 0);
        if (k + 2 < C_ / BK) {
#pragma unroll
            for (int ta = 0; ta < 4; ++ta)   // issue L2 B-frags for k+2
                bcur[ta] = *(const bf16x8*)(srcB + (size_t)(ta * 16) * C_ + (size_t)(k + 2) * 32);
            *(unsigned long long*)&As[0][a_off] = pack4bf(av0);
        }
        WG_BARRIER();
    }

    // ---- epilogue: relu + dot(w_full), reduce over a ---------------------
    const int col = l16, quad = lq;
#pragma unroll
    for (int tr = 0; tr < 4; ++tr) {
        int rgl = tr * 16 + col;
        int bi  = (row0 + rgl) / 196 - b0;
        float s = 0.0f;
#pragma unroll
        for (int ta = 0; ta < 4; ++ta)
#pragma unroll
            for (int rr = 0; rr < 4; ++rr) {
                int a_idx = wa * 64 + ta * 16 + quad * 4 + rr;
                float v = acc[ta][tr][rr] + decL[bi][a_idx];
                s = fmaf(fmaxf(v, 0.0f), wL[a_idx], s);
            }
        s += __shfl_xor(s, 16);
        s += __shfl_xor(s, 32);
        if (quad == 0) att_part[wa][rgl] = s;
    }
    __syncthreads();
    if (t < BM) {
        float s = bfull[0];
#pragma unroll
        for (int w = 0; w < 8; ++w) s += att_part[w][t];
        att[row0 + t] = s;
    }
}

// ---------------------------------------------------------------------------
// Kernel 4: softmax over 196 pixels per batch (1 wave per batch)
// ---------------------------------------------------------------------------
__global__ __launch_bounds__(64) void k_softmax(const float* __restrict__ att,
                                                float* __restrict__ alpha) {
    int b = blockIdx.x, lane = threadIdx.x;
    const float* a = att + b * P_;
    float v[4];
    float mx = -__builtin_inff();
#pragma unroll
    for (int i = 0; i < 4; ++i) {
        int p = lane + i * 64;
        v[i] = (p < P_) ? a[p] : -__builtin_inff();
        mx = fmaxf(mx, v[i]);
    }
#pragma unroll
    for (int off = 32; off >= 1; off >>= 1) mx = fmaxf(mx, __shfl_xor(mx, off));
    float sum = 0.0f;
#pragma unroll
    for (int i = 0; i < 4; ++i) {
        int p = lane + i * 64;
        float e = (p < P_) ? expf(v[i] - mx) : 0.0f;
        v[i] = e;
        sum += e;
    }
#pragma unroll
    for (int off = 32; off >= 1; off >>= 1) sum += __shfl_xor(sum, off);
    float inv = 1.0f / sum;
#pragma unroll
    for (int i = 0; i < 4; ++i) {
        int p = lane + i * 64;
        if (p < P_) alpha[b * P_ + p] = v[i] * inv;
    }
}

// ---------------------------------------------------------------------------
// Kernel 5: context[b][c] = sum_p enc[b][c][p] * alpha[b][p]   (fp32 exact)
// Rebuilt: block = (b, 64-c chunk), 4 waves; each wave: 4 rows/pass via
// 16-lane groups (full lane utilization, 256B segments), alpha hoisted to
// registers once, 4-shuffle reduce.  Purely HBM-streaming.
// ---------------------------------------------------------------------------
__global__ __launch_bounds__(256) void k_context(const float* __restrict__ enc,
                                                 const float* __restrict__ alpha,
                                                 float* __restrict__ ctx) {
    __shared__ float aL[200];
    int t = threadIdx.x;
    int b = blockIdx.x >> 5;
    int chunk = blockIdx.x & 31;
    if (t < P_) aL[t] = alpha[b * P_ + t];
    __syncthreads();
    int wv = t >> 6, l = t & 63, g = l >> 4, j = l & 15;
    float4 a0 = *(const float4*)&aL[j * 4];         // p =   0..63  (lane-fixed)
    float4 a1 = *(const float4*)&aL[64 + j * 4];    // p =  64..127
    float4 a2 = *(const float4*)&aL[128 + j * 4];   // p = 128..191
    float4 a3 = *(const float4*)&aL[192];           // p = 192..195 (uniform)
    const float* base = enc + (size_t)b * CP_ + (size_t)(chunk * 64) * P_;
#pragma unroll
    for (int pass = 0; pass < 4; ++pass) {
        int r = wv * 16 + pass * 4 + g;             // 0..63, bijective
        const float* row = base + (size_t)r * P_;
        float4 f0 = *(const float4*)(row + j * 4);
        float4 f1 = *(const float4*)(row + 64 + j * 4);
        float4 f2 = *(const float4*)(row + 128 + j * 4);
        float s = f0.x * a0.x + f0.y * a0.y + f0.z * a0.z + f0.w * a0.w;
        s += f1.x * a1.x + f1.y * a1.y + f1.z * a1.z + f1.w * a1.w;
        s += f2.x * a2.x + f2.y * a2.y + f2.z * a2.z + f2.w * a2.w;
        if (j == 0) {
            float4 f3 = *(const float4*)(row + 192);
            s += f3.x * a3.x + f3.y * a3.y + f3.z * a3.z + f3.w * a3.w;
        }
        s += __shfl_xor(s, 1);
        s += __shfl_xor(s, 2);
        s += __shfl_xor(s, 4);
        s += __shfl_xor(s, 8);
        if (j == 0) ctx[(size_t)b * C_ + chunk * 64 + r] = s;
    }
}

// ---------------------------------------------------------------------------
extern "C" void kernel_launch(void* const* d_in, const int* in_sizes, int n_in,
                              void* d_out, int out_size, void* d_ws, size_t ws_size,
                              hipStream_t stream) {
    const float* enc   = (const float*)d_in[0];
    const float* dh    = (const float*)d_in[1];
    const float* Wenc  = (const float*)d_in[2];
    const float* benc  = (const float*)d_in[3];
    const float* Wdec  = (const float*)d_in[4];
    const float* bdec  = (const float*)d_in[5];
    const float* wfull = (const float*)d_in[6];
    const float* bfull = (const float*)d_in[7];

    u16*   Wt  = (u16*)d_ws;                                        // 2 MB
    float* dec = (float*)((char*)d_ws + (2u << 20));                // 512 KB
    float* att = (float*)((char*)d_ws + (2u << 20) + (512u << 10)); // 200 KB

    float* ctx     = (float*)d_out;          // [256][2048]
    float* alpha_o = ctx + B_ * C_;          // [256][196]

    k_transpose_wenc<<<dim3(256), dim3(256), 0, stream>>>(Wenc, Wt);
    k_dec_att<<<dim3(256), dim3(512), 0, stream>>>(dh, Wdec, bdec, dec);
    k_gemm_att<<<dim3(NBLK), dim3(512), 0, stream>>>(enc, Wt, dec, benc,
                                                     wfull, bfull, att);
    k_softmax<<<dim3(256), dim3(64), 0, stream>>>(att, alpha_o);
    k_context<<<dim3(256 * 32), dim3(256), 0, stream>>>(enc, alpha_o, ctx);
}